// Round 2
// baseline (1111.215 us; speedup 1.0000x reference)
//
#include <hip/hip_runtime.h>
#include <stdint.h>

// ---------------------------------------------------------------------------
// Exact JAX Threefry-2x32 (jax/_src/prng.py schedule; Random123 constants).
// rotations[0]={13,15,26,6} (rounds 0,2,4), rotations[1]={17,29,16,24} (1,3)
// ---------------------------------------------------------------------------
__host__ __device__ inline void threefry2x32(uint32_t k0, uint32_t k1,
                                             uint32_t x0, uint32_t x1,
                                             uint32_t& o0, uint32_t& o1) {
  const uint32_t ks2 = k0 ^ k1 ^ 0x1BD11BDAu;
#define TF_ROUND(r) { x0 += x1; x1 = (x1 << (r)) | (x1 >> (32 - (r))); x1 ^= x0; }
  x0 += k0; x1 += k1;
  TF_ROUND(13) TF_ROUND(15) TF_ROUND(26) TF_ROUND(6)
  x0 += k1;  x1 += ks2 + 1u;
  TF_ROUND(17) TF_ROUND(29) TF_ROUND(16) TF_ROUND(24)
  x0 += ks2; x1 += k0 + 2u;
  TF_ROUND(13) TF_ROUND(15) TF_ROUND(26) TF_ROUND(6)
  x0 += k0;  x1 += k1 + 3u;
  TF_ROUND(17) TF_ROUND(29) TF_ROUND(16) TF_ROUND(24)
  x0 += k1;  x1 += ks2 + 4u;
  TF_ROUND(13) TF_ROUND(15) TF_ROUND(26) TF_ROUND(6)
  x0 += ks2; x1 += k0 + 5u;
#undef TF_ROUND
  o0 = x0; o1 = x1;
}

// jax_threefry_partitionable=True stream, 32-bit draws:
//   bits[i] = o0 ^ o1 where (o0,o1) = threefry(key, (i>>32, i&0xffffffff))
__device__ inline uint32_t jax_bits_partitionable(uint32_t k0, uint32_t k1,
                                                  uint32_t ctr_lo) {
  uint32_t o0, o1;
  threefry2x32(k0, k1, 0u, ctr_lo, o0, o1);  // n < 2^32 -> high word is 0
  return o0 ^ o1;
}

// uniform [0,1) from 32 random bits, exactly as jax.random.uniform does it
__device__ inline float bits_to_uniform(uint32_t bits) {
  return __uint_as_float((bits >> 9) | 0x3f800000u) - 1.0f;
}

// quantize one value: floor(v/sigma + r)*sigma clipped to [tmin, tmax]
__device__ inline float qround(float v, uint32_t bits, float sigma,
                               float inv_sigma, float tmin, float tmax) {
  float r = bits_to_uniform(bits);
  // v*inv_sigma is exact (pow-2 scale) -> identical result with/without fma
  float t = floorf(v * inv_sigma + r) * sigma;
  return fminf(fmaxf(t, tmin), tmax);
}

// ---------------------------------------------------------------------------
// Kernel A: overflow/underflow counts at sigma0 thresholds.
// counts[0] = #(x > tmax0) + #(x < tmin0); counts[1] = same at half-thresholds
// ---------------------------------------------------------------------------
__global__ __launch_bounds__(256) void count_kernel(
    const float* __restrict__ x, long long n,
    unsigned int* __restrict__ counts,
    float tmax, float tmin, float htmax, float htmin) {
  long long idx = (long long)blockIdx.x * blockDim.x + threadIdx.x;
  long long stride = (long long)gridDim.x * blockDim.x;
  long long n4 = n >> 2;
  const float4* x4 = (const float4*)x;
  unsigned int over = 0, under = 0;
  for (long long i = idx; i < n4; i += stride) {
    float4 v = x4[i];
    over  += (v.x > tmax)  + (v.x < tmin)  + (v.y > tmax)  + (v.y < tmin)
           + (v.z > tmax)  + (v.z < tmin)  + (v.w > tmax)  + (v.w < tmin);
    under += (v.x > htmax) + (v.x < htmin) + (v.y > htmax) + (v.y < htmin)
           + (v.z > htmax) + (v.z < htmin) + (v.w > htmax) + (v.w < htmin);
  }
  // scalar tail (n not divisible by 4)
  for (long long i = (n4 << 2) + idx; i < n; i += stride) {
    float v = x[i];
    over  += (v > tmax)  + (v < tmin);
    under += (v > htmax) + (v < htmin);
  }
  // counts are ~0 for sane data: conditional atomic -> near-zero contention
  if (over)  atomicAdd(&counts[0], over);
  if (under) atomicAdd(&counts[1], under);
}

// ---------------------------------------------------------------------------
// Kernel B: compute sigma from counts, then stochastic-round.
// Partitionable stream: element i uses counter (0, i), bits = o0^o1.
// Each thread serves 4 consecutive elements (float4 load/store, 4 threefrys).
// ---------------------------------------------------------------------------
__global__ __launch_bounds__(256) void quant_kernel(
    const float* __restrict__ x, float* __restrict__ out,
    long long n, const unsigned int* __restrict__ counts,
    float inv_n, uint32_t k0, uint32_t k1) {
  float overflow  = (float)counts[0] * inv_n;   // exact: inv_n = 2^-27
  float underflow = (float)counts[1] * inv_n;
  // sigma = where(over > .01, 2s, where(under < .01, s/2, s)), s = 0.25
  float sigma = (overflow > 0.01f) ? 0.5f
              : ((underflow < 0.01f) ? 0.125f : 0.25f);
  float tmax = sigma * 128.0f - sigma;
  float tmin = sigma * -128.0f;
  float inv_sigma = 1.0f / sigma;               // exact pow-2

  long long n4 = n >> 2;
  long long idx = (long long)blockIdx.x * blockDim.x + threadIdx.x;
  long long stride = (long long)gridDim.x * blockDim.x;
  const float4* x4 = (const float4*)x;
  float4* o4 = (float4*)out;

  for (long long i = idx; i < n4; i += stride) {
    float4 v = x4[i];
    uint32_t c = (uint32_t)(i << 2);
    uint32_t b0 = jax_bits_partitionable(k0, k1, c + 0u);
    uint32_t b1 = jax_bits_partitionable(k0, k1, c + 1u);
    uint32_t b2 = jax_bits_partitionable(k0, k1, c + 2u);
    uint32_t b3 = jax_bits_partitionable(k0, k1, c + 3u);
    v.x = qround(v.x, b0, sigma, inv_sigma, tmin, tmax);
    v.y = qround(v.y, b1, sigma, inv_sigma, tmin, tmax);
    v.z = qround(v.z, b2, sigma, inv_sigma, tmin, tmax);
    v.w = qround(v.w, b3, sigma, inv_sigma, tmin, tmax);
    o4[i] = v;
  }
  // scalar tail (n not divisible by 4)
  for (long long j = (n4 << 2) + idx; j < n; j += stride) {
    uint32_t b = jax_bits_partitionable(k0, k1, (uint32_t)j);
    out[j] = qround(x[j], b, sigma, inv_sigma, tmin, tmax);
  }
}

extern "C" void kernel_launch(void* const* d_in, const int* in_sizes, int n_in,
                              void* d_out, int out_size, void* d_ws, size_t ws_size,
                              hipStream_t stream) {
  const float* x = (const float*)d_in[0];
  float* out = (float*)d_out;
  long long n = (long long)in_sizes[0];   // 134217728 = 2^27

  unsigned int* counts = (unsigned int*)d_ws;
  hipMemsetAsync(counts, 0, 2 * sizeof(unsigned int), stream);

  // host-side: rkey = fold_in(key(42), 0) = threefry_2x32((0,42), seed_key(0))
  // fold_in path is config-independent: threefry((0,42),(0,0)) -> (o0,o1)
  uint32_t k0, k1;
  threefry2x32(0u, 42u, 0u, 0u, k0, k1);

  const float sigma0 = 0.25f;
  const float tmax0 = sigma0 * 128.0f - sigma0;   // 31.75
  const float tmin0 = -sigma0 * 128.0f;           // -32
  const float htmax0 = 0.5f * tmax0;              // 15.875
  const float htmin0 = 0.5f * tmin0;              // -16

  const int block = 256;
  long long n4 = n >> 2;
  long long grid_c = (n4 + block - 1) / block;
  if (grid_c < 1) grid_c = 1;
  if (grid_c > 131072) grid_c = 131072;
  count_kernel<<<(dim3)(unsigned)grid_c, block, 0, stream>>>(
      x, n, counts, tmax0, tmin0, htmax0, htmin0);

  long long grid_q = (n4 + block - 1) / block;
  if (grid_q < 1) grid_q = 1;
  if (grid_q > 131072) grid_q = 131072;
  float inv_n = 1.0f / (float)n;
  quant_kernel<<<(dim3)(unsigned)grid_q, block, 0, stream>>>(
      x, out, n, counts, inv_n, k0, k1);
}